// Round 1
// baseline (273.171 us; speedup 1.0000x reference)
//
#include <hip/hip_runtime.h>

#define NN 1024      // nodes per graph
#define DG 8         // neighbors per node
#define FO 64        // output features
#define FI 128       // input features
#define LALPHA 0.2f  // leaky relu slope

// ---------------------------------------------------------------------------
// Kernel U: dedupe each node's 8 neighbor indices (duplicates -> -1).
// adjacency is built with .set(1.0): duplicate edges collapse to a single 1.
// ---------------------------------------------------------------------------
__global__ __launch_bounds__(256) void k_uniq(const int* __restrict__ edges,
                                              int* __restrict__ uniq, int nrows) {
  int r = blockIdx.x * 256 + threadIdx.x;
  if (r >= nrows) return;
  int e[DG];
#pragma unroll
  for (int s = 0; s < DG; s++) e[s] = edges[r * DG + s];
#pragma unroll
  for (int s = 0; s < DG; s++) {
    int v = e[s];
    bool dup = false;
#pragma unroll
    for (int q = 0; q < DG; q++)
      if (q < s && e[q] == v) dup = true;
    uniq[r * DG + s] = dup ? -1 : v;
  }
}

// ---------------------------------------------------------------------------
// Kernel A: h = atom @ W  (per row), plus src = h@a[:64], dst = h@a[64:]
// 4 rows per block; wave w handles row, lane = feature f (wave64).
// ---------------------------------------------------------------------------
__global__ __launch_bounds__(256) void k_h(const float* __restrict__ atoms,
                                           const float* __restrict__ W,
                                           const float* __restrict__ a,
                                           float* __restrict__ h,
                                           float* __restrict__ srcv,
                                           float* __restrict__ dstv) {
  __shared__ float Wl[FI * FO];   // 32 KB
  __shared__ float Al[4 * FI];    // 2 KB
  const int t = threadIdx.x;
  const int b = blockIdx.x;
  for (int idx = t; idx < FI * FO; idx += 256) Wl[idx] = W[idx];
  for (int idx = t; idx < 4 * FI; idx += 256) Al[idx] = atoms[b * 4 * FI + idx];
  __syncthreads();
  const int w = t >> 6, f = t & 63;
  float acc = 0.f;
#pragma unroll 8
  for (int c = 0; c < FI; c++) acc += Al[w * FI + c] * Wl[c * FO + f];
  const int row = b * 4 + w;
  h[row * FO + f] = acc;
  float sp = acc * a[f];
  float dp = acc * a[FO + f];
#pragma unroll
  for (int off = 32; off > 0; off >>= 1) {
    sp += __shfl_down(sp, off);
    dp += __shfl_down(dp, off);
  }
  if (f == 0) { srcv[row] = sp; dstv[row] = dp; }
}

// ---------------------------------------------------------------------------
// Kernel C: colsum[g][f] = sum_i h[g][i][f]
// ---------------------------------------------------------------------------
__global__ __launch_bounds__(256) void k_colsum(const float* __restrict__ h,
                                                float* __restrict__ colsum) {
  const int g = blockIdx.x, t = threadIdx.x;
  const int f = t & 63, q = t >> 6;
  float s = 0.f;
  for (int i = q * 256; i < q * 256 + 256; i++) s += h[(g * NN + i) * FO + f];
  __shared__ float part[4][FO];
  part[q][f] = s;
  __syncthreads();
  if (q == 0) colsum[g * FO + f] = part[0][f] + part[1][f] + part[2][f] + part[3][f];
}

// ---------------------------------------------------------------------------
// Kernel B: one block per (graph g, node i).
//  1. scatter S_i = (A + A^2 + A^3) row into LDS (<=584 LDS atomics)
//  2. att softmax over unique neighbors (exp(-9e15) == 0 exactly in fp32)
//  3. compact nonzeros of S, e_j = exp(S_ij)-1, Z = 1024 + sum e_j
//  4. out = elu(0.5*att@h + 0.5*(colsum + sum e_j h_j)/Z)
// ---------------------------------------------------------------------------
__global__ __launch_bounds__(256) void k_main(const int* __restrict__ uniq,
                                              const float* __restrict__ h,
                                              const float* __restrict__ srcv,
                                              const float* __restrict__ dstv,
                                              const float* __restrict__ colsum,
                                              float* __restrict__ out) {
  __shared__ float S[NN];                       // 4 KB dense row accumulator
  __shared__ float2 pairs[DG + DG * DG + DG * DG * DG];  // (col,e) compacted, 584 max
  __shared__ int n1[DG];
  __shared__ int list2[DG * DG];
  __shared__ float attw[DG];
  __shared__ float2 part2[4][2][32];
  __shared__ float2 partA[32];
  __shared__ float zred[4];
  __shared__ int cnt;
  __shared__ float Zs;

  const int t = threadIdx.x;
  const int b = blockIdx.x;       // global row index
  const int g = b >> 10;          // graph

  for (int idx = t; idx < NN; idx += 256) S[idx] = 0.f;
  if (t < DG) n1[t] = uniq[b * DG + t];
  if (t == 0) cnt = 0;
  __syncthreads();

  // level 1: A_i
  if (t < DG) {
    int j = n1[t];
    if (j >= 0) atomicAdd(&S[j], 1.f);
  }
  // level 2: A^2_i, record the (j,k) multiset for level 3
  if (t < DG * DG) {
    int j = n1[t >> 3];
    int k = -1;
    if (j >= 0) k = uniq[(g * NN + j) * DG + (t & 7)];
    list2[t] = k;
    if (k >= 0) atomicAdd(&S[k], 1.f);
  }
  __syncthreads();
  // level 3: A^3_i = sum over (j,k) pairs of A_k rows
  for (int idx = t; idx < DG * DG * DG; idx += 256) {
    int k = list2[idx >> 3];
    if (k >= 0) {
      int l = uniq[(g * NN + k) * DG + (idx & 7)];
      if (l >= 0) atomicAdd(&S[l], 1.f);
    }
  }

  // attention softmax over unique neighbors (serial, <=8 terms)
  if (t == 0) {
    float si = srcv[b];
    float ev[DG];
    float m = -1e30f;
#pragma unroll
    for (int s = 0; s < DG; s++) {
      int j = n1[s];
      if (j >= 0) {
        float x = si + dstv[g * NN + j];
        x = x > 0.f ? x : LALPHA * x;  // leaky_relu
        ev[s] = x;
        m = fmaxf(m, x);
      } else ev[s] = -1e30f;
    }
    float sm = 0.f;
#pragma unroll
    for (int s = 0; s < DG; s++) {
      float e = (n1[s] >= 0) ? __expf(ev[s] - m) : 0.f;
      ev[s] = e;
      sm += e;
    }
    float inv = 1.f / sm;
#pragma unroll
    for (int s = 0; s < DG; s++) attw[s] = ev[s] * inv;
  }
  __syncthreads();

  // compact nonzeros + Z partial
  float zp = 0.f;
  for (int idx = t; idx < NN; idx += 256) {
    float v = S[idx];
    if (v > 0.f) {
      float e = __expf(v) - 1.f;
      int p = atomicAdd(&cnt, 1);
      pairs[p] = make_float2(__int_as_float(idx), e);
      zp += e;
    }
  }
#pragma unroll
  for (int off = 32; off > 0; off >>= 1) zp += __shfl_down(zp, off);
  if ((t & 63) == 0) zred[t >> 6] = zp;
  __syncthreads();
  if (t == 0) Zs = (float)NN + zred[0] + zred[1] + zred[2] + zred[3];
  __syncthreads();

  // gather-accumulate: acc[f] = sum_p e_p * h[col_p][f], float2 vectorized.
  // wave w handles pairs {w*2+sub, stride 8}; lanes 0..31 / 32..63 split p.
  const int w = t >> 6, lane = t & 63, sub = lane >> 5, f2 = lane & 31;
  const float2* hg2 = (const float2*)(h + g * NN * FO);
  float2 acc = make_float2(0.f, 0.f);
  const int nn = cnt;
  for (int p = w * 2 + sub; p < nn; p += 8) {
    float2 pr = pairs[p];
    int j = __float_as_int(pr.x);
    float2 hv = hg2[j * 32 + f2];
    acc.x += pr.y * hv.x;
    acc.y += pr.y * hv.y;
  }
  part2[w][sub][f2] = acc;
  if (t < 32) {  // att @ h (<=8 terms)
    float2 aacc = make_float2(0.f, 0.f);
#pragma unroll
    for (int s = 0; s < DG; s++) {
      int j = n1[s];
      if (j >= 0) {
        float2 hv = hg2[j * 32 + t];
        float aw = attw[s];
        aacc.x += aw * hv.x;
        aacc.y += aw * hv.y;
      }
    }
    partA[t] = aacc;
  }
  __syncthreads();

  if (t < 32) {
    float2 tot = make_float2(0.f, 0.f);
#pragma unroll
    for (int ww = 0; ww < 4; ww++)
#pragma unroll
      for (int ss = 0; ss < 2; ss++) {
        float2 v = part2[ww][ss][t];
        tot.x += v.x;
        tot.y += v.y;
      }
    const float2 cs = ((const float2*)colsum)[g * 32 + t];
    const float invZ = 1.f / Zs;
    float2 at = partA[t];
    float bx = 0.5f * at.x + 0.5f * (cs.x + tot.x) * invZ;
    float by = 0.5f * at.y + 0.5f * (cs.y + tot.y) * invZ;
    bx = bx > 0.f ? bx : __expf(bx) - 1.f;  // elu (alpha=1)
    by = by > 0.f ? by : __expf(by) - 1.f;
    ((float2*)out)[b * 32 + t] = make_float2(bx, by);
  }
}

// ---------------------------------------------------------------------------
extern "C" void kernel_launch(void* const* d_in, const int* in_sizes, int n_in,
                              void* d_out, int out_size, void* d_ws, size_t ws_size,
                              hipStream_t stream) {
  const float* atoms = (const float*)d_in[0];
  const int* edges = (const int*)d_in[1];
  const float* W = (const float*)d_in[2];
  const float* a = (const float*)d_in[3];
  float* out = (float*)d_out;

  const int nrows = in_sizes[0] / FI;   // B*N = 16384
  const int ngraph = nrows / NN;        // 16

  // workspace layout (all written before read each launch; ws is re-poisoned)
  float* ws = (float*)d_ws;
  float* h = ws;                              // nrows*FO
  float* srcv = h + (size_t)nrows * FO;       // nrows
  float* dstv = srcv + nrows;                 // nrows
  float* colsum = dstv + nrows;               // ngraph*FO
  int* uniq = (int*)(colsum + ngraph * FO);   // nrows*DG ints

  k_uniq<<<(nrows + 255) / 256, 256, 0, stream>>>(edges, uniq, nrows);
  k_h<<<nrows / 4, 256, 0, stream>>>(atoms, W, a, h, srcv, dstv);
  k_colsum<<<ngraph, 256, 0, stream>>>(h, colsum);
  k_main<<<nrows, 256, 0, stream>>>(uniq, h, srcv, dstv, colsum, out);
}

// Round 2
// 175.141 us; speedup vs baseline: 1.5597x; 1.5597x over previous
//
#include <hip/hip_runtime.h>

#define NN 1024
#define DG 8
#define FO 64
#define FI 128
#define LALPHA 0.2f

typedef __attribute__((ext_vector_type(8))) short bf16x8;
typedef __attribute__((ext_vector_type(4))) float f32x4;

static __device__ __forceinline__ unsigned short f2bf(float x) {
  union { float f; unsigned u; } v; v.f = x;
  unsigned r = v.u + 0x7FFFu + ((v.u >> 16) & 1u);  // round-to-nearest-even
  return (unsigned short)(r >> 16);
}

// ---------------------------------------------------------------------------
// K1: dedupe neighbor lists (duplicates -> -1); .set(1.0) collapses dups.
// ---------------------------------------------------------------------------
__global__ __launch_bounds__(256) void k_uniq(const int* __restrict__ edges,
                                              int* __restrict__ uniq, int nrows) {
  int r = blockIdx.x * 256 + threadIdx.x;
  if (r >= nrows) return;
  int e[DG];
#pragma unroll
  for (int s = 0; s < DG; s++) e[s] = edges[r * DG + s];
#pragma unroll
  for (int s = 0; s < DG; s++) {
    int v = e[s];
    bool dup = false;
#pragma unroll
    for (int q = 0; q < DG; q++)
      if (q < s && e[q] == v) dup = true;
    uniq[r * DG + s] = dup ? -1 : v;
  }
}

// ---------------------------------------------------------------------------
// K2: h = atom@W (bf16 out), src/dst rank-1 projections (fp32).
// W transposed into LDS once -> float4 reads (1 b128 per 4 MACs).
// 8 rows/block, 2 rows per thread sharing each W read.
// ---------------------------------------------------------------------------
__global__ __launch_bounds__(256) void k_h(const float* __restrict__ atoms,
                                           const float* __restrict__ W,
                                           const float* __restrict__ a,
                                           ushort* __restrict__ hb,
                                           float* __restrict__ srcv,
                                           float* __restrict__ dstv) {
  __shared__ __align__(16) float WT[FO * 132];  // [f][c], pad 132
  __shared__ __align__(16) float Al[8 * FI];
  const int t = threadIdx.x, b = blockIdx.x;
  for (int i = t; i < FI * FO; i += 256) {
    int c = i >> 6, f = i & 63;
    WT[f * 132 + c] = W[i];
  }
  for (int i = t; i < 8 * FI; i += 256) Al[i] = atoms[b * 8 * FI + i];
  __syncthreads();
  const int w = t >> 6, f = t & 63;
  const float as = a[f], ad = a[FO + f];
  const float4* wt4 = (const float4*)&WT[f * 132];
  const float4* a04 = (const float4*)&Al[(2 * w) * FI];
  const float4* a14 = (const float4*)&Al[(2 * w + 1) * FI];
  float acc0 = 0.f, acc1 = 0.f;
#pragma unroll
  for (int c = 0; c < FI / 4; c++) {
    float4 wv = wt4[c], x0 = a04[c], x1 = a14[c];
    acc0 += x0.x * wv.x + x0.y * wv.y + x0.z * wv.z + x0.w * wv.w;
    acc1 += x1.x * wv.x + x1.y * wv.y + x1.z * wv.z + x1.w * wv.w;
  }
  const int r0 = b * 8 + 2 * w, r1 = r0 + 1;
  hb[r0 * FO + f] = f2bf(acc0);
  hb[r1 * FO + f] = f2bf(acc1);
  float s0 = acc0 * as, d0 = acc0 * ad, s1 = acc1 * as, d1 = acc1 * ad;
#pragma unroll
  for (int off = 32; off > 0; off >>= 1) {
    s0 += __shfl_down(s0, off);
    d0 += __shfl_down(d0, off);
    s1 += __shfl_down(s1, off);
    d1 += __shfl_down(d1, off);
  }
  if (f == 0) { srcv[r0] = s0; dstv[r0] = d0; srcv[r1] = s1; dstv[r1] = d1; }
}

// ---------------------------------------------------------------------------
// K3: build dense blended matrix M (bf16), 16 rows/block, 2 rows concurrent.
// M[i][j] = 0.5*att_ij + (0.5/Z_i)*exp(S_ij), S = A+A^2+A^3 counts.
// Whole graph's uniq table staged in LDS -> scatter is pure LDS.
// ---------------------------------------------------------------------------
__global__ __launch_bounds__(256) void k_build(const int* __restrict__ uniq,
                                               const float* __restrict__ srcv,
                                               const float* __restrict__ dstv,
                                               ushort* __restrict__ Mb) {
  __shared__ int U[NN * DG];        // 32 KB
  __shared__ float S[2][NN];        // 8 KB
  __shared__ float attD[2][NN];     // 8 KB
  __shared__ float attw[16][DG];
  __shared__ float zpart[2][2];
  const int t = threadIdx.x, b = blockIdx.x;
  const int g = b >> 6, rbase = (b & 63) * 16;

  for (int i = t; i < NN * DG; i += 256) U[i] = uniq[g * NN * DG + i];
  __syncthreads();

  // att softmax for the block's 16 rows (one thread per row)
  if (t < 16) {
    int lr = rbase + t;
    float si = srcv[g * NN + lr];
    float ev[DG];
    float m = -1e30f;
#pragma unroll
    for (int s = 0; s < DG; s++) {
      int j = U[lr * DG + s];
      if (j >= 0) {
        float x = si + dstv[g * NN + j];
        x = x > 0.f ? x : LALPHA * x;
        ev[s] = x;
        m = fmaxf(m, x);
      } else ev[s] = -1e30f;
    }
    float sm = 0.f;
#pragma unroll
    for (int s = 0; s < DG; s++) {
      float e = (U[lr * DG + s] >= 0) ? __expf(ev[s] - m) : 0.f;
      ev[s] = e;
      sm += e;
    }
    float inv = 1.f / sm;
#pragma unroll
    for (int s = 0; s < DG; s++) attw[t][s] = ev[s] * inv;
  }
  __syncthreads();

  const int half = t >> 7, t2 = t & 127;
  for (int rr = 0; rr < 16; rr += 2) {
    const int lrow = rr + half;            // row slot 0..15
    const int lr = rbase + lrow;           // node index in graph
    float* Sh = S[half];
    float* aD = attD[half];
    for (int i = t2; i < NN; i += 128) { Sh[i] = 0.f; aD[i] = 0.f; }
    __syncthreads();

    // scatter: att (plain, unique cols), levels 1..3 (LDS atomics)
    if (t2 < DG) {
      int j = U[lr * DG + t2];
      if (j >= 0) {
        aD[j] = 0.5f * attw[lrow][t2];
        atomicAdd(&Sh[j], 1.f);
      }
    }
    if (t2 < DG * DG) {
      int j = U[lr * DG + (t2 >> 3)];
      if (j >= 0) {
        int k = U[j * DG + (t2 & 7)];
        if (k >= 0) atomicAdd(&Sh[k], 1.f);
      }
    }
#pragma unroll
    for (int q = 0; q < 4; q++) {
      int idx = t2 * 4 + q;  // 0..511
      int j = U[lr * DG + (idx >> 6)];
      if (j >= 0) {
        int k = U[j * DG + ((idx >> 3) & 7)];
        if (k >= 0) {
          int l = U[k * DG + (idx & 7)];
          if (l >= 0) atomicAdd(&Sh[l], 1.f);
        }
      }
    }
    __syncthreads();

    // pass1: E = exp(S) in place, Z = sum E (exp(0)=1 covers the dense base)
    const int c0 = t2 * 8;
    float zp = 0.f;
#pragma unroll
    for (int e = 0; e < 8; e++) {
      float E = __expf(Sh[c0 + e]);
      Sh[c0 + e] = E;
      zp += E;
    }
#pragma unroll
    for (int off = 32; off > 0; off >>= 1) zp += __shfl_down(zp, off);
    if ((t2 & 63) == 0) zpart[half][t2 >> 6] = zp;
    __syncthreads();
    const float hzi = 0.5f / (zpart[half][0] + zpart[half][1]);

    // pass2: pack 8 bf16 and store 16B coalesced
    union { uint4 v; ushort u[8]; } pk;
#pragma unroll
    for (int e = 0; e < 8; e++)
      pk.u[e] = f2bf(hzi * Sh[c0 + e] + aD[c0 + e]);
    *(uint4*)(Mb + ((size_t)(g * NN + lr)) * NN + c0) = pk.v;
    __syncthreads();
  }
}

// ---------------------------------------------------------------------------
// K4: out = elu(M @ h), bf16 MFMA 16x16x32, fp32 accum.
// Block: 32 out-rows x 64 cols, K=1024 in 16 chunks of 64.
// ---------------------------------------------------------------------------
__global__ __launch_bounds__(256) void k_gemm(const ushort* __restrict__ Mb,
                                              const ushort* __restrict__ hb,
                                              float* __restrict__ out) {
  __shared__ __align__(16) ushort Mt[32 * 72];  // [r][k] pad 72
  __shared__ __align__(16) ushort hT[64 * 72];  // [f][k] pad 72
  const int t = threadIdx.x, b = blockIdx.x;
  const int g = b >> 5, it = b & 31;
  const ushort* Mg = Mb + ((size_t)(g * NN + it * 32)) * NN;
  const ushort* hg = hb + (size_t)g * NN * FO;
  const int w = t >> 6, lane = t & 63;
  const int rw = w >> 1, nw = w & 1;
  const int quad = lane >> 4, l16 = lane & 15;
  f32x4 acc0 = {0.f, 0.f, 0.f, 0.f}, acc1 = {0.f, 0.f, 0.f, 0.f};

  const int mrow = t >> 3, mc = (t & 7) * 8;   // M stage job
  const int hkr = t >> 3, hf0 = (t & 7) * 8;   // h stage jobs (2 halves)

  for (int kc = 0; kc < NN; kc += 64) {
    uint4 mv = *(const uint4*)(Mg + (size_t)mrow * NN + kc + mc);
    uint4 h0 = *(const uint4*)(hg + (size_t)(kc + hkr) * FO + hf0);
    uint4 h1 = *(const uint4*)(hg + (size_t)(kc + 32 + hkr) * FO + hf0);
    __syncthreads();  // previous chunk fully consumed
    *(uint4*)(&Mt[mrow * 72 + mc]) = mv;
    union { uint4 v; ushort u[8]; } a0, a1;
    a0.v = h0; a1.v = h1;
#pragma unroll
    for (int e = 0; e < 8; e++) {
      hT[(hf0 + e) * 72 + hkr] = a0.u[e];
      hT[(hf0 + e) * 72 + hkr + 32] = a1.u[e];
    }
    __syncthreads();
#pragma unroll
    for (int ks = 0; ks < 64; ks += 32) {
      bf16x8 af = *(const bf16x8*)(&Mt[(rw * 16 + l16) * 72 + ks + quad * 8]);
      bf16x8 b0 = *(const bf16x8*)(&hT[(nw * 32 + l16) * 72 + ks + quad * 8]);
      bf16x8 b1 = *(const bf16x8*)(&hT[(nw * 32 + 16 + l16) * 72 + ks + quad * 8]);
      acc0 = __builtin_amdgcn_mfma_f32_16x16x32_bf16(af, b0, acc0, 0, 0, 0);
      acc1 = __builtin_amdgcn_mfma_f32_16x16x32_bf16(af, b1, acc1, 0, 0, 0);
    }
  }

  // epilogue: C/D layout col=lane&15, row=quad*4+reg
#pragma unroll
  for (int r = 0; r < 4; r++) {
    int i = it * 32 + rw * 16 + quad * 4 + r;
    int f = nw * 32 + l16;
    float v0 = acc0[r];
    v0 = v0 > 0.f ? v0 : __expf(v0) - 1.f;
    out[((size_t)(g * NN + i)) * FO + f] = v0;
    float v1 = acc1[r];
    v1 = v1 > 0.f ? v1 : __expf(v1) - 1.f;
    out[((size_t)(g * NN + i)) * FO + f + 16] = v1;
  }
}

// ---------------------------------------------------------------------------
extern "C" void kernel_launch(void* const* d_in, const int* in_sizes, int n_in,
                              void* d_out, int out_size, void* d_ws, size_t ws_size,
                              hipStream_t stream) {
  const float* atoms = (const float*)d_in[0];
  const int* edges = (const int*)d_in[1];
  const float* W = (const float*)d_in[2];
  const float* a = (const float*)d_in[3];
  float* out = (float*)d_out;

  const int nrows = in_sizes[0] / FI;   // B*N = 16384
  const int ngraph = nrows / NN;        // 16

  // workspace: Mb (bf16 dense blended) | hb (bf16 h) | srcv | dstv | uniq
  ushort* Mb = (ushort*)d_ws;                                   // ngraph*NN*NN
  ushort* hb = Mb + (size_t)ngraph * NN * NN;                   // nrows*FO
  float* srcv = (float*)(hb + (size_t)nrows * FO);              // nrows
  float* dstv = srcv + nrows;                                   // nrows
  int* uniq = (int*)(dstv + nrows);                             // nrows*DG

  k_uniq<<<(nrows + 255) / 256, 256, 0, stream>>>(edges, uniq, nrows);
  k_h<<<nrows / 8, 256, 0, stream>>>(atoms, W, a, hb, srcv, dstv);
  k_build<<<ngraph * 64, 256, 0, stream>>>(uniq, srcv, dstv, Mb);
  k_gemm<<<ngraph * 32, 256, 0, stream>>>(Mb, hb, out);
}

// Round 3
// 120.404 us; speedup vs baseline: 2.2688x; 1.4546x over previous
//
#include <hip/hip_runtime.h>

#define NN 1024
#define DG 8
#define FO 64
#define FI 128
#define LALPHA 0.2f

typedef __attribute__((ext_vector_type(8))) short bf16x8;
typedef __attribute__((ext_vector_type(4))) float f32x4;

static __device__ __forceinline__ unsigned short f2bf(float x) {
  union { float f; unsigned u; } v; v.f = x;
  unsigned r = v.u + 0x7FFFu + ((v.u >> 16) & 1u);  // round-to-nearest-even
  return (unsigned short)(r >> 16);
}
static __device__ __forceinline__ float bf2f(unsigned short h) {
  union { unsigned u; float f; } v; v.u = ((unsigned)h) << 16;
  return v.f;
}

// ---------------------------------------------------------------------------
// K1: dedupe neighbor lists (duplicates -> -1); .set(1.0) collapses dups.
// ---------------------------------------------------------------------------
__global__ __launch_bounds__(256) void k_uniq(const int* __restrict__ edges,
                                              int* __restrict__ uniq, int nrows) {
  int r = blockIdx.x * 256 + threadIdx.x;
  if (r >= nrows) return;
  int e[DG];
#pragma unroll
  for (int s = 0; s < DG; s++) e[s] = edges[r * DG + s];
#pragma unroll
  for (int s = 0; s < DG; s++) {
    int v = e[s];
    bool dup = false;
#pragma unroll
    for (int q = 0; q < DG; q++)
      if (q < s && e[q] == v) dup = true;
    uniq[r * DG + s] = dup ? -1 : v;
  }
}

// ---------------------------------------------------------------------------
// K2: h = atom@W via bf16 MFMA with hi/lo compensation (3 MFMAs ~ fp32).
// 64 rows/block, 4 waves (wave w = rows w*16..+16, all 64 cols).
// Outputs: hT[g][f][node] (bf16, pre-transposed for k_gemm), srcv/dstv fp32.
// ---------------------------------------------------------------------------
__global__ __launch_bounds__(256) void k_h(const float* __restrict__ atoms,
                                           const float* __restrict__ W,
                                           const float* __restrict__ a,
                                           ushort* __restrict__ hT,
                                           float* __restrict__ srcv,
                                           float* __restrict__ dstv) {
  __shared__ __align__(16) ushort Ahi[64 * 136], Alo[64 * 136];   // [row][k]
  __shared__ __align__(16) ushort Whi[64 * 136], Wlo[64 * 136];   // [f][k]
  __shared__ float al[2 * FO];
  const int t = threadIdx.x, b = blockIdx.x;

  // stage atoms (64x128 fp32 -> hi/lo bf16)
  const float4* at4 = (const float4*)(atoms + (size_t)b * 64 * FI);
#pragma unroll
  for (int q = 0; q < 8; q++) {
    int idx = t + 256 * q;                 // 2048 float4
    float4 v = at4[idx];
    int row = idx >> 5, c4 = (idx & 31) * 4;
    ushort h0 = f2bf(v.x), h1 = f2bf(v.y), h2 = f2bf(v.z), h3 = f2bf(v.w);
    ushort l0 = f2bf(v.x - bf2f(h0)), l1 = f2bf(v.y - bf2f(h1));
    ushort l2_ = f2bf(v.z - bf2f(h2)), l3 = f2bf(v.w - bf2f(h3));
    union { uint2 v; ushort u[4]; } ph, pl;
    ph.u[0] = h0; ph.u[1] = h1; ph.u[2] = h2; ph.u[3] = h3;
    pl.u[0] = l0; pl.u[1] = l1; pl.u[2] = l2_; pl.u[3] = l3;
    *(uint2*)&Ahi[row * 136 + c4] = ph.v;
    *(uint2*)&Alo[row * 136 + c4] = pl.v;
  }
  // stage W transposed (W[c][f] -> WT[f][c]) hi/lo
  const float4* w4 = (const float4*)W;
#pragma unroll
  for (int q = 0; q < 8; q++) {
    int idx = t + 256 * q;                 // 2048 float4 = 8192 floats
    float4 v = w4[idx];
    int c = idx >> 4, f0 = (idx & 15) * 4;
    float vv[4] = {v.x, v.y, v.z, v.w};
#pragma unroll
    for (int e = 0; e < 4; e++) {
      ushort hi = f2bf(vv[e]);
      Whi[(f0 + e) * 136 + c] = hi;
      Wlo[(f0 + e) * 136 + c] = f2bf(vv[e] - bf2f(hi));
    }
  }
  if (t < 2 * FO) al[t] = a[t];
  __syncthreads();

  const int w = t >> 6, lane = t & 63, quad = lane >> 4, l16 = lane & 15;
  f32x4 acc[4] = {{0.f, 0.f, 0.f, 0.f}, {0.f, 0.f, 0.f, 0.f},
                  {0.f, 0.f, 0.f, 0.f}, {0.f, 0.f, 0.f, 0.f}};
#pragma unroll
  for (int kc = 0; kc < 4; kc++) {
    int ko = kc * 32 + quad * 8;
    bf16x8 ahi = *(const bf16x8*)&Ahi[(w * 16 + l16) * 136 + ko];
    bf16x8 alo = *(const bf16x8*)&Alo[(w * 16 + l16) * 136 + ko];
#pragma unroll
    for (int ct = 0; ct < 4; ct++) {
      bf16x8 bhi = *(const bf16x8*)&Whi[(ct * 16 + l16) * 136 + ko];
      bf16x8 blo = *(const bf16x8*)&Wlo[(ct * 16 + l16) * 136 + ko];
      acc[ct] = __builtin_amdgcn_mfma_f32_16x16x32_bf16(ahi, bhi, acc[ct], 0, 0, 0);
      acc[ct] = __builtin_amdgcn_mfma_f32_16x16x32_bf16(ahi, blo, acc[ct], 0, 0, 0);
      acc[ct] = __builtin_amdgcn_mfma_f32_16x16x32_bf16(alo, bhi, acc[ct], 0, 0, 0);
    }
  }

  // epilogue: lane holds rows quad*4+r, col ct*16+l16 per ct.
  const int g = b >> 4;
  float ps[4] = {0.f, 0.f, 0.f, 0.f}, pd[4] = {0.f, 0.f, 0.f, 0.f};
#pragma unroll
  for (int ct = 0; ct < 4; ct++) {
    int f = ct * 16 + l16;
    float as_ = al[f], ad_ = al[FO + f];
#pragma unroll
    for (int r = 0; r < 4; r++) {
      float v = acc[ct][r];
      int rb = b * 64 + w * 16 + quad * 4 + r;  // global row
      int n = rb & (NN - 1);
      hT[((size_t)g * FO + f) * NN + n] = f2bf(v);
      ps[r] += v * as_;
      pd[r] += v * ad_;
    }
  }
#pragma unroll
  for (int off = 8; off > 0; off >>= 1)
#pragma unroll
    for (int r = 0; r < 4; r++) {
      ps[r] += __shfl_xor(ps[r], off);
      pd[r] += __shfl_xor(pd[r], off);
    }
  if (l16 == 0) {
#pragma unroll
    for (int r = 0; r < 4; r++) {
      int rb = b * 64 + w * 16 + quad * 4 + r;
      srcv[rb] = ps[r];
      dstv[rb] = pd[r];
    }
  }
}

// ---------------------------------------------------------------------------
// K3: build dense blended M (bf16), 8 rows/block all-concurrent.
// S counts in u8 byte-lanes of u32 LDS words (max count 73 < 255, no carry).
// M[i][j] = (exp(S_ij) + att_ij*Z_i) * (0.5/Z_i). 6 barriers/block.
// ---------------------------------------------------------------------------
#define BR 8
__global__ __launch_bounds__(256) void k_build(const int* __restrict__ uniq,
                                               const float* __restrict__ srcv,
                                               const float* __restrict__ dstv,
                                               ushort* __restrict__ Mb) {
  __shared__ unsigned Sb[BR * 256];     // 8 KB byte counters
  __shared__ float Mrow[BR * NN];       // 32 KB
  __shared__ int n1[BR][DG];
  __shared__ int l2[BR][64];
  __shared__ float attw[BR][DG];
  __shared__ float zl[BR * 32];
  __shared__ float Zr[BR];
  const int t = threadIdx.x, b = blockIdx.x;
  const int g = b >> 7, rbase = (b & 127) * BR;
  const int* __restrict__ Ug = uniq + (size_t)g * NN * DG;

  for (int i = t; i < BR * 256; i += 256) Sb[i] = 0u;
  if (t < BR * DG) n1[t >> 3][t & 7] = Ug[(rbase + (t >> 3)) * DG + (t & 7)];
  __syncthreads();

  // threads 0..63: level-1 + level-2 scatter and l2 list; 64..71: att softmax
  if (t < 64) {
    int r = t >> 3, s = t & 7;
    int j = n1[r][s];
    if (j >= 0) {
      atomicAdd(&Sb[r * 256 + (j >> 2)], 1u << ((j & 3) * 8));
      int4 k0 = *(const int4*)(Ug + j * DG);
      int4 k1 = *(const int4*)(Ug + j * DG + 4);
      int kk[8] = {k0.x, k0.y, k0.z, k0.w, k1.x, k1.y, k1.z, k1.w};
#pragma unroll
      for (int e = 0; e < 8; e++) {
        l2[r][s * 8 + e] = kk[e];
        if (kk[e] >= 0) atomicAdd(&Sb[r * 256 + (kk[e] >> 2)], 1u << ((kk[e] & 3) * 8));
      }
    } else {
#pragma unroll
      for (int e = 0; e < 8; e++) l2[r][s * 8 + e] = -1;
    }
  } else if (t < 64 + BR) {
    int r = t - 64;
    float si = srcv[g * NN + rbase + r];
    float ev[DG];
    float m = -1e30f;
#pragma unroll
    for (int s = 0; s < DG; s++) {
      int j = n1[r][s];
      if (j >= 0) {
        float x = si + dstv[g * NN + j];
        x = x > 0.f ? x : LALPHA * x;
        ev[s] = x;
        m = fmaxf(m, x);
      } else ev[s] = -1e30f;
    }
    float sm = 0.f;
#pragma unroll
    for (int s = 0; s < DG; s++) {
      float e = (n1[r][s] >= 0) ? __expf(ev[s] - m) : 0.f;
      ev[s] = e;
      sm += e;
    }
    float inv = 1.f / sm;
#pragma unroll
    for (int s = 0; s < DG; s++) attw[r][s] = ev[s] * inv;
  }
  __syncthreads();

  // level-3: 512 items (r, e), 2 per thread
#pragma unroll
  for (int q = 0; q < 2; q++) {
    int idx = t + 256 * q;
    int r = idx >> 6, e = idx & 63;
    int k = l2[r][e];
    if (k >= 0) {
      int4 m0 = *(const int4*)(Ug + k * DG);
      int4 m1 = *(const int4*)(Ug + k * DG + 4);
      int ll[8] = {m0.x, m0.y, m0.z, m0.w, m1.x, m1.y, m1.z, m1.w};
#pragma unroll
      for (int e2 = 0; e2 < 8; e2++)
        if (ll[e2] >= 0) atomicAdd(&Sb[r * 256 + (ll[e2] >> 2)], 1u << ((ll[e2] & 3) * 8));
    }
  }
  __syncthreads();

  // exp phase: r = t>>5, u = t&31, 8 words (32 cols) per thread
  {
    int r = t >> 5, u = t & 31;
    float zp = 0.f;
#pragma unroll
    for (int cc = 0; cc < 8; cc++) {
      int wd = cc * 32 + u;
      unsigned sv = Sb[r * 256 + wd];
      float e0 = __expf((float)(sv & 255u));
      float e1 = __expf((float)((sv >> 8) & 255u));
      float e2 = __expf((float)((sv >> 16) & 255u));
      float e3 = __expf((float)(sv >> 24));
      float4 ev = make_float4(e0, e1, e2, e3);
      *(float4*)&Mrow[r * NN + wd * 4] = ev;
      zp += e0 + e1 + e2 + e3;
    }
    zl[r * 32 + u] = zp;
  }
  __syncthreads();
  if (t < BR) {
    float s = 0.f;
#pragma unroll
    for (int u = 0; u < 32; u++) s += zl[t * 32 + u];
    Zr[t] = s;
  }
  __syncthreads();
  // att fold-in: M += att*Z (scaled by 0.5/Z below -> 0.5*att)
  if (t < 64) {
    int r = t >> 3, s = t & 7;
    int j = n1[r][s];
    if (j >= 0) Mrow[r * NN + j] += attw[r][s] * Zr[r];
  }
  __syncthreads();
  // pack + store
  {
    int r = t >> 5, u = t & 31;
    float hzi = 0.5f / Zr[r];
    size_t orow = (size_t)(g * NN + rbase + r) * NN;
#pragma unroll
    for (int cc2 = 0; cc2 < 4; cc2++) {
      int c0 = cc2 * 256 + u * 8;
      float4 v0 = *(const float4*)&Mrow[r * NN + c0];
      float4 v1 = *(const float4*)&Mrow[r * NN + c0 + 4];
      union { uint4 v; ushort u[8]; } pk;
      pk.u[0] = f2bf(hzi * v0.x); pk.u[1] = f2bf(hzi * v0.y);
      pk.u[2] = f2bf(hzi * v0.z); pk.u[3] = f2bf(hzi * v0.w);
      pk.u[4] = f2bf(hzi * v1.x); pk.u[5] = f2bf(hzi * v1.y);
      pk.u[6] = f2bf(hzi * v1.z); pk.u[7] = f2bf(hzi * v1.w);
      *(uint4*)(Mb + orow + c0) = pk.v;
    }
  }
}

// ---------------------------------------------------------------------------
// K4: out = elu(M @ h), bf16 MFMA. 32 rows x 64 cols per block, K-chunks 128.
// h comes pre-transposed (hT[f][node]) -> staging is pure coalesced uint4.
// ---------------------------------------------------------------------------
__global__ __launch_bounds__(256) void k_gemm(const ushort* __restrict__ Mb,
                                              const ushort* __restrict__ hTg,
                                              float* __restrict__ out) {
  __shared__ __align__(16) ushort Mt[32 * 136];  // [r][k]
  __shared__ __align__(16) ushort hT[64 * 136];  // [f][k]
  const int t = threadIdx.x, b = blockIdx.x;
  const int g = b >> 5, it = b & 31;
  const ushort* __restrict__ Mg = Mb + (size_t)(g * NN + it * 32) * NN;
  const ushort* __restrict__ hg = hTg + (size_t)g * FO * NN;
  const int w = t >> 6, lane = t & 63, quad = lane >> 4, l16 = lane & 15;
  const int rg = w >> 1, cg = w & 1;
  f32x4 acc0 = {0.f, 0.f, 0.f, 0.f}, acc1 = {0.f, 0.f, 0.f, 0.f};

  for (int kc = 0; kc < NN; kc += 128) {
    // M: 32 rows x 128 k = 512 uint4 jobs; h: 64 f x 128 k = 1024 uint4 jobs
    uint4 mv[2], hv[4];
    int mrow[2], mk[2], hf[4], hk[4];
#pragma unroll
    for (int q = 0; q < 2; q++) {
      int idx = t + 256 * q;
      mrow[q] = idx >> 4; mk[q] = (idx & 15) * 8;
      mv[q] = *(const uint4*)(Mg + (size_t)mrow[q] * NN + kc + mk[q]);
    }
#pragma unroll
    for (int q = 0; q < 4; q++) {
      int idx = t + 256 * q;
      hf[q] = idx >> 4; hk[q] = (idx & 15) * 8;
      hv[q] = *(const uint4*)(hg + (size_t)hf[q] * NN + kc + hk[q]);
    }
    __syncthreads();
#pragma unroll
    for (int q = 0; q < 2; q++) *(uint4*)&Mt[mrow[q] * 136 + mk[q]] = mv[q];
#pragma unroll
    for (int q = 0; q < 4; q++) *(uint4*)&hT[hf[q] * 136 + hk[q]] = hv[q];
    __syncthreads();
#pragma unroll
    for (int ks = 0; ks < 128; ks += 32) {
      bf16x8 af = *(const bf16x8*)&Mt[(rg * 16 + l16) * 136 + ks + quad * 8];
      bf16x8 b0 = *(const bf16x8*)&hT[(cg * 32 + l16) * 136 + ks + quad * 8];
      bf16x8 b1 = *(const bf16x8*)&hT[(cg * 32 + 16 + l16) * 136 + ks + quad * 8];
      acc0 = __builtin_amdgcn_mfma_f32_16x16x32_bf16(af, b0, acc0, 0, 0, 0);
      acc1 = __builtin_amdgcn_mfma_f32_16x16x32_bf16(af, b1, acc1, 0, 0, 0);
    }
  }

#pragma unroll
  for (int r = 0; r < 4; r++) {
    int i = it * 32 + rg * 16 + quad * 4 + r;
    int f = cg * 32 + l16;
    float v0 = acc0[r];
    v0 = v0 > 0.f ? v0 : __expf(v0) - 1.f;
    out[((size_t)(g * NN + i)) * FO + f] = v0;
    float v1 = acc1[r];
    v1 = v1 > 0.f ? v1 : __expf(v1) - 1.f;
    out[((size_t)(g * NN + i)) * FO + f + 16] = v1;
  }
}

// ---------------------------------------------------------------------------
extern "C" void kernel_launch(void* const* d_in, const int* in_sizes, int n_in,
                              void* d_out, int out_size, void* d_ws, size_t ws_size,
                              hipStream_t stream) {
  const float* atoms = (const float*)d_in[0];
  const int* edges = (const int*)d_in[1];
  const float* W = (const float*)d_in[2];
  const float* a = (const float*)d_in[3];
  float* out = (float*)d_out;

  const int nrows = in_sizes[0] / FI;   // B*N = 16384
  const int ngraph = nrows / NN;        // 16

  ushort* Mb = (ushort*)d_ws;                                   // ngraph*NN*NN
  ushort* hT = Mb + (size_t)ngraph * NN * NN;                   // ngraph*FO*NN
  float* srcv = (float*)(hT + (size_t)ngraph * FO * NN);        // nrows
  float* dstv = srcv + nrows;                                   // nrows
  int* uniq = (int*)(dstv + nrows);                             // nrows*DG

  k_uniq<<<(nrows + 255) / 256, 256, 0, stream>>>(edges, uniq, nrows);
  k_h<<<nrows / 64, 256, 0, stream>>>(atoms, W, a, hT, srcv, dstv);
  k_build<<<ngraph * (NN / BR), 256, 0, stream>>>(uniq, srcv, dstv, Mb);
  k_gemm<<<ngraph * (NN / 32), 256, 0, stream>>>(Mb, hT, out);
}

// Round 4
// 99.544 us; speedup vs baseline: 2.7442x; 1.2096x over previous
//
#include <hip/hip_runtime.h>

#define NN 1024
#define DG 8
#define FO 64
#define FI 128
#define LALPHA 0.2f
#define BR 16        // output rows per fused block
#define SBS 257      // Sb row stride (u32 words), odd -> dense reads 2-way/free
#define MTS 1032     // Mt row stride (ushorts); 516 words = 4 mod 32 (m97 pattern)

typedef __attribute__((ext_vector_type(8))) short bf16x8;
typedef __attribute__((ext_vector_type(4))) float f32x4;

static __device__ __forceinline__ unsigned short f2bf(float x) {
  union { float f; unsigned u; } v; v.f = x;
  unsigned r = v.u + 0x7FFFu + ((v.u >> 16) & 1u);  // round-to-nearest-even
  return (unsigned short)(r >> 16);
}
static __device__ __forceinline__ float bf2f(unsigned short h) {
  union { unsigned u; float f; } v; v.u = ((unsigned)h) << 16;
  return v.f;
}

// ---------------------------------------------------------------------------
// K1: dedupe neighbor lists (duplicates -> -1); .set(1.0) collapses dups.
// ---------------------------------------------------------------------------
__global__ __launch_bounds__(256) void k_uniq(const int* __restrict__ edges,
                                              int* __restrict__ uniq, int nrows) {
  int r = blockIdx.x * 256 + threadIdx.x;
  if (r >= nrows) return;
  int e[DG];
#pragma unroll
  for (int s = 0; s < DG; s++) e[s] = edges[r * DG + s];
#pragma unroll
  for (int s = 0; s < DG; s++) {
    int v = e[s];
    bool dup = false;
#pragma unroll
    for (int q = 0; q < DG; q++)
      if (q < s && e[q] == v) dup = true;
    uniq[r * DG + s] = dup ? -1 : v;
  }
}

// ---------------------------------------------------------------------------
// K2: h = atom@W via bf16 MFMA with hi/lo compensation (3 MFMAs ~ fp32).
// Outputs hT[g][f][node] (bf16, transposed: B-fragment-ready), srcv/dstv fp32.
// ---------------------------------------------------------------------------
__global__ __launch_bounds__(256) void k_h(const float* __restrict__ atoms,
                                           const float* __restrict__ W,
                                           const float* __restrict__ a,
                                           ushort* __restrict__ hT,
                                           float* __restrict__ srcv,
                                           float* __restrict__ dstv) {
  __shared__ __align__(16) ushort Ahi[64 * 136], Alo[64 * 136];   // [row][k]
  __shared__ __align__(16) ushort Whi[64 * 136], Wlo[64 * 136];   // [f][k]
  __shared__ float al[2 * FO];
  const int t = threadIdx.x, b = blockIdx.x;

  const float4* at4 = (const float4*)(atoms + (size_t)b * 64 * FI);
#pragma unroll
  for (int q = 0; q < 8; q++) {
    int idx = t + 256 * q;                 // 2048 float4
    float4 v = at4[idx];
    int row = idx >> 5, c4 = (idx & 31) * 4;
    ushort h0 = f2bf(v.x), h1 = f2bf(v.y), h2 = f2bf(v.z), h3 = f2bf(v.w);
    ushort l0 = f2bf(v.x - bf2f(h0)), l1 = f2bf(v.y - bf2f(h1));
    ushort l2_ = f2bf(v.z - bf2f(h2)), l3 = f2bf(v.w - bf2f(h3));
    union { uint2 v; ushort u[4]; } ph, pl;
    ph.u[0] = h0; ph.u[1] = h1; ph.u[2] = h2; ph.u[3] = h3;
    pl.u[0] = l0; pl.u[1] = l1; pl.u[2] = l2_; pl.u[3] = l3;
    *(uint2*)&Ahi[row * 136 + c4] = ph.v;
    *(uint2*)&Alo[row * 136 + c4] = pl.v;
  }
  const float4* w4 = (const float4*)W;
#pragma unroll
  for (int q = 0; q < 8; q++) {
    int idx = t + 256 * q;
    float4 v = w4[idx];
    int c = idx >> 4, f0 = (idx & 15) * 4;
    float vv[4] = {v.x, v.y, v.z, v.w};
#pragma unroll
    for (int e = 0; e < 4; e++) {
      ushort hi = f2bf(vv[e]);
      Whi[(f0 + e) * 136 + c] = hi;
      Wlo[(f0 + e) * 136 + c] = f2bf(vv[e] - bf2f(hi));
    }
  }
  if (t < 2 * FO) al[t] = a[t];
  __syncthreads();

  const int w = t >> 6, lane = t & 63, quad = lane >> 4, l16 = lane & 15;
  f32x4 acc[4] = {{0.f, 0.f, 0.f, 0.f}, {0.f, 0.f, 0.f, 0.f},
                  {0.f, 0.f, 0.f, 0.f}, {0.f, 0.f, 0.f, 0.f}};
#pragma unroll
  for (int kc = 0; kc < 4; kc++) {
    int ko = kc * 32 + quad * 8;
    bf16x8 ahi = *(const bf16x8*)&Ahi[(w * 16 + l16) * 136 + ko];
    bf16x8 alo = *(const bf16x8*)&Alo[(w * 16 + l16) * 136 + ko];
#pragma unroll
    for (int ct = 0; ct < 4; ct++) {
      bf16x8 bhi = *(const bf16x8*)&Whi[(ct * 16 + l16) * 136 + ko];
      bf16x8 blo = *(const bf16x8*)&Wlo[(ct * 16 + l16) * 136 + ko];
      acc[ct] = __builtin_amdgcn_mfma_f32_16x16x32_bf16(ahi, bhi, acc[ct], 0, 0, 0);
      acc[ct] = __builtin_amdgcn_mfma_f32_16x16x32_bf16(ahi, blo, acc[ct], 0, 0, 0);
      acc[ct] = __builtin_amdgcn_mfma_f32_16x16x32_bf16(alo, bhi, acc[ct], 0, 0, 0);
    }
  }

  const int g = b >> 4;
  float ps[4] = {0.f, 0.f, 0.f, 0.f}, pd[4] = {0.f, 0.f, 0.f, 0.f};
#pragma unroll
  for (int ct = 0; ct < 4; ct++) {
    int f = ct * 16 + l16;
    float as_ = al[f], ad_ = al[FO + f];
#pragma unroll
    for (int r = 0; r < 4; r++) {
      float v = acc[ct][r];
      int rb = b * 64 + w * 16 + quad * 4 + r;
      int n = rb & (NN - 1);
      hT[((size_t)g * FO + f) * NN + n] = f2bf(v);
      ps[r] += v * as_;
      pd[r] += v * ad_;
    }
  }
#pragma unroll
  for (int off = 8; off > 0; off >>= 1)
#pragma unroll
    for (int r = 0; r < 4; r++) {
      ps[r] += __shfl_xor(ps[r], off);
      pd[r] += __shfl_xor(pd[r], off);
    }
  if (l16 == 0) {
#pragma unroll
    for (int r = 0; r < 4; r++) {
      int rb = b * 64 + w * 16 + quad * 4 + r;
      srcv[rb] = ps[r];
      dstv[rb] = pd[r];
    }
  }
}

// ---------------------------------------------------------------------------
// K3 (fused): build 16-row blended M strip in LDS (never touches HBM), then
// MFMA it against L2-resident hT, fused elu epilogue. 6 barriers/block.
// S counts in u8 byte-lanes of u32 (max count 73 < 255, no carry).
// M[i][j] = 0.5*att_ij + (0.5/Z_i)*exp(S_ij).
// ---------------------------------------------------------------------------
__global__ __launch_bounds__(256) void k_fused(const int* __restrict__ uniq,
                                               const float* __restrict__ srcv,
                                               const float* __restrict__ dstv,
                                               const ushort* __restrict__ hT,
                                               float* __restrict__ out) {
  __shared__ unsigned Sb[BR * SBS];            // 16.4 KB byte counters
  __shared__ __align__(16) ushort Mt[BR * MTS];  // 33 KB bf16 M strip
  __shared__ int n1[BR][DG];
  __shared__ float attw[BR][DG];
  __shared__ float zl[BR][16];
  __shared__ float Zr[BR];

  const int t = threadIdx.x, b = blockIdx.x;
  const int g = b >> 6, rbase = (b & 63) * BR;
  const int* __restrict__ Ug = uniq + (size_t)g * NN * DG;

  for (int i = t; i < BR * SBS; i += 256) Sb[i] = 0u;
  if (t < BR * DG) n1[t >> 3][t & 7] = Ug[(rbase + (t >> 3)) * DG + (t & 7)];
  __syncthreads();

  // level-1 + level-2 scatter (threads 0..127); att softmax (128..143)
  if (t < 128) {
    int r = t >> 3, s = t & 7;
    int j = n1[r][s];
    if (j >= 0) {
      atomicAdd(&Sb[r * SBS + (j >> 2)], 1u << ((j & 3) * 8));
      int4 k0 = *(const int4*)(Ug + j * DG);
      int4 k1 = *(const int4*)(Ug + j * DG + 4);
      int kk[8] = {k0.x, k0.y, k0.z, k0.w, k1.x, k1.y, k1.z, k1.w};
#pragma unroll
      for (int e = 0; e < 8; e++)
        if (kk[e] >= 0) atomicAdd(&Sb[r * SBS + (kk[e] >> 2)], 1u << ((kk[e] & 3) * 8));
    }
  } else if (t < 128 + BR) {
    int r = t - 128;
    float si = srcv[g * NN + rbase + r];
    float ev[DG];
    float m = -1e30f;
#pragma unroll
    for (int s = 0; s < DG; s++) {
      int j = n1[r][s];
      if (j >= 0) {
        float x = si + dstv[g * NN + j];
        x = x > 0.f ? x : LALPHA * x;
        ev[s] = x;
        m = fmaxf(m, x);
      } else ev[s] = -1e30f;
    }
    float sm = 0.f;
#pragma unroll
    for (int s = 0; s < DG; s++) {
      float e = (n1[r][s] >= 0) ? __expf(ev[s] - m) : 0.f;
      ev[s] = e;
      sm += e;
    }
    float inv = 1.f / sm;
#pragma unroll
    for (int s = 0; s < DG; s++) attw[r][s] = ev[s] * inv;
  }
  // level-3 scatter: 1024 (row, pair) items, 4 per thread, y re-derived from L2
#pragma unroll
  for (int q = 0; q < 4; q++) {
    int idx = t + 256 * q;
    int r = idx >> 6, e = idx & 63;
    int j = n1[r][e >> 3];
    if (j >= 0) {
      int k = Ug[j * DG + (e & 7)];
      if (k >= 0) {
        int4 m0 = *(const int4*)(Ug + k * DG);
        int4 m1 = *(const int4*)(Ug + k * DG + 4);
        int ll[8] = {m0.x, m0.y, m0.z, m0.w, m1.x, m1.y, m1.z, m1.w};
#pragma unroll
        for (int e2 = 0; e2 < 8; e2++)
          if (ll[e2] >= 0) atomicAdd(&Sb[r * SBS + (ll[e2] >> 2)], 1u << ((ll[e2] & 3) * 8));
      }
    }
  }
  __syncthreads();

  // Z pass: row r = t&15 (fast index -> bank-clean), 64 cols per thread
  {
    int r = t & 15, u = t >> 4;
    float zp = 0.f;
#pragma unroll
    for (int q = 0; q < 16; q++) {
      unsigned sv = Sb[r * SBS + u * 16 + q];
      zp += __expf((float)(sv & 255u)) + __expf((float)((sv >> 8) & 255u)) +
            __expf((float)((sv >> 16) & 255u)) + __expf((float)(sv >> 24));
    }
    zl[r][u] = zp;
  }
  __syncthreads();
  if (t < BR) {
    float s = 0.f;
#pragma unroll
    for (int u = 0; u < 16; u++) s += zl[t][u];
    Zr[t] = s;
  }
  __syncthreads();

  // write M strip: bf16, uint4 stores (8 cols each)
  {
    int r = t & 15, u = t >> 4;
    float hzi = 0.5f / Zr[r];
#pragma unroll
    for (int q = 0; q < 8; q++) {
      unsigned s0 = Sb[r * SBS + u * 16 + 2 * q];
      unsigned s1 = Sb[r * SBS + u * 16 + 2 * q + 1];
      union { uint4 v; ushort us[8]; } pk;
      pk.us[0] = f2bf(hzi * __expf((float)(s0 & 255u)));
      pk.us[1] = f2bf(hzi * __expf((float)((s0 >> 8) & 255u)));
      pk.us[2] = f2bf(hzi * __expf((float)((s0 >> 16) & 255u)));
      pk.us[3] = f2bf(hzi * __expf((float)(s0 >> 24)));
      pk.us[4] = f2bf(hzi * __expf((float)(s1 & 255u)));
      pk.us[5] = f2bf(hzi * __expf((float)((s1 >> 8) & 255u)));
      pk.us[6] = f2bf(hzi * __expf((float)((s1 >> 16) & 255u)));
      pk.us[7] = f2bf(hzi * __expf((float)(s1 >> 24)));
      *(uint4*)&Mt[r * MTS + u * 64 + q * 8] = pk.v;
    }
  }
  __syncthreads();
  // att fold-in (sparse, unique cols per row)
  if (t < 128) {
    int r = t >> 3, s = t & 7;
    int j = n1[r][s];
    if (j >= 0) {
      int adr = r * MTS + j;
      Mt[adr] = f2bf(bf2f(Mt[adr]) + 0.5f * attw[r][s]);
    }
  }
  __syncthreads();

  // GEMM: wave w -> out cols w*16..+16; A from LDS Mt, B direct from L2 hT.
  const int w = t >> 6, lane = t & 63, quad = lane >> 4, l16 = lane & 15;
  const ushort* __restrict__ hrow = hT + ((size_t)g * FO + w * 16 + l16) * NN;
  f32x4 acc = {0.f, 0.f, 0.f, 0.f};
#pragma unroll 4
  for (int ks = 0; ks < NN; ks += 32) {
    bf16x8 af = *(const bf16x8*)&Mt[l16 * MTS + ks + quad * 8];
    bf16x8 bf = *(const bf16x8*)(hrow + ks + quad * 8);
    acc = __builtin_amdgcn_mfma_f32_16x16x32_bf16(af, bf, acc, 0, 0, 0);
  }
#pragma unroll
  for (int r = 0; r < 4; r++) {
    int row = rbase + quad * 4 + r;
    float v = acc[r];
    v = v > 0.f ? v : __expf(v) - 1.f;
    out[((size_t)(g * NN + row)) * FO + w * 16 + l16] = v;
  }
}

// ---------------------------------------------------------------------------
extern "C" void kernel_launch(void* const* d_in, const int* in_sizes, int n_in,
                              void* d_out, int out_size, void* d_ws, size_t ws_size,
                              hipStream_t stream) {
  const float* atoms = (const float*)d_in[0];
  const int* edges = (const int*)d_in[1];
  const float* W = (const float*)d_in[2];
  const float* a = (const float*)d_in[3];
  float* out = (float*)d_out;

  const int nrows = in_sizes[0] / FI;   // B*N = 16384
  const int ngraph = nrows / NN;        // 16

  ushort* hT = (ushort*)d_ws;                                   // ngraph*FO*NN
  float* srcv = (float*)(hT + (size_t)ngraph * FO * NN);        // nrows
  float* dstv = srcv + nrows;                                   // nrows
  int* uniq = (int*)(dstv + nrows);                             // nrows*DG

  k_uniq<<<(nrows + 255) / 256, 256, 0, stream>>>(edges, uniq, nrows);
  k_h<<<nrows / 64, 256, 0, stream>>>(atoms, W, a, hT, srcv, dstv);
  k_fused<<<ngraph * (NN / BR), 256, 0, stream>>>(uniq, srcv, dstv, hT, out);
}